// Round 10
// baseline (400.933 us; speedup 1.0000x reference)
//
#include <hip/hip_runtime.h>
#include <hip/hip_bf16.h>
#include <cstddef>

// ToxicityGAT: 2-layer GAT (4 heads -> 1 head) + linear classifier.
// N=50000, E=800000 (+N self loops), IN=128, HID=64, HEADS=4.
// R10: agg1 batch 8->12, agg2 batch 16->32 (same MLP axis as R6's win),
// selfloop merged into scan3. agg1 is otherwise at the ~2.3 TB/s
// L2-miss-path floor (195 MB misses; R3/R6 convergence evidence).

#define HEADS 4
#define HID 64
#define IN_DIM 128

using bf16x8 = __attribute__((ext_vector_type(8))) short;
using f32x4  = __attribute__((ext_vector_type(4))) float;

__device__ __forceinline__ float us2f(unsigned short u) {
    return __uint_as_float((unsigned int)u << 16);
}
__device__ __forceinline__ unsigned short f2us(float f) {
    __hip_bfloat16 b = __float2bfloat16(f);
    return __builtin_bit_cast(unsigned short, b);
}

// ---------------- setup: deg init + W1/W2 transpose+bf16 (one launch) ------
__global__ __launch_bounds__(256) void setup_kernel(const float* __restrict__ W1,
                                                    const float* __restrict__ W2,
                                                    unsigned short* __restrict__ W1T,
                                                    unsigned short* __restrict__ W2T,
                                                    int* __restrict__ deg, int N) {
    int i = blockIdx.x * 256 + threadIdx.x;
    if (i < N) deg[i] = 1;                       // self loop
    if (i < IN_DIM * 256) {                      // W1 [128][256] -> W1T [256][128]
        int k = i >> 8, n = i & 255;
        W1T[n * IN_DIM + k] = f2us(W1[i]);
    }
    if (i < 256 * 64) {                          // W2 [256][64] -> W2T [64][256]
        int k = i >> 6, n = i & 63;
        W2T[n * 256 + k] = f2us(W2[i]);
    }
}

// ---------------- MFMA GEMM + fused alpha dots ------------------------------
// C = A @ BT^T. AF32: A fp32->bf16 during staging. INTERLEAVE: g1b[n][d][h].
// NHEAD>0: epilogue computes per-row per-head dots with att_src/att_dst
// (requires BN == Nfull so each wave owns full rows).
template <int BN, int BK, int KFULL, bool INTERLEAVE, bool AF32, int NHEAD>
__global__ __launch_bounds__(256) void gemm_mfma_kernel(
    const void* __restrict__ Av,
    const unsigned short* __restrict__ BT,
    unsigned short* __restrict__ C,
    const float* __restrict__ att_src, const float* __restrict__ att_dst,
    float* __restrict__ as_out, float* __restrict__ ad_out,
    int M, int Nfull) {
    constexpr int LDK = BK + 8;
    constexpr int NT = BN / 16;
    constexpr int KC = BK / 8;
    __shared__ unsigned short As[64 * LDK];
    __shared__ unsigned short Bs[BN * LDK];
    const int tid = threadIdx.x;
    const int wave = tid >> 6, lane = tid & 63;
    const int row0 = blockIdx.y * 64;
    const int col0 = blockIdx.x * BN;
    f32x4 acc[NT] = {};
    for (int k0 = 0; k0 < KFULL; k0 += BK) {
        for (int c = tid; c < 64 * KC; c += 256) {
            int r = c / KC, kc = c - r * KC;
            int row = row0 + r; if (row >= M) row = M - 1;  // clamp: stay in-bounds
            if constexpr (AF32) {
                const float* src = (const float*)Av + (size_t)row * KFULL + k0 + kc * 8;
                float4 v0 = *(const float4*)(src);
                float4 v1 = *(const float4*)(src + 4);
                *(ushort4*)(As + r * LDK + kc * 8) =
                    make_ushort4(f2us(v0.x), f2us(v0.y), f2us(v0.z), f2us(v0.w));
                *(ushort4*)(As + r * LDK + kc * 8 + 4) =
                    make_ushort4(f2us(v1.x), f2us(v1.y), f2us(v1.z), f2us(v1.w));
            } else {
                *(bf16x8*)(As + r * LDK + kc * 8) =
                    *(const bf16x8*)((const unsigned short*)Av + (size_t)row * KFULL + k0 + kc * 8);
            }
        }
        for (int c = tid; c < BN * KC; c += 256) {
            int r = c / KC, kc = c - r * KC;
            *(bf16x8*)(Bs + r * LDK + kc * 8) =
                *(const bf16x8*)(BT + (size_t)(col0 + r) * KFULL + k0 + kc * 8);
        }
        __syncthreads();
        const int arow = wave * 16 + (lane & 15);
        const int kb = (lane >> 4) * 8;
#pragma unroll
        for (int ks = 0; ks < BK; ks += 32) {
            bf16x8 af = *(const bf16x8*)(As + arow * LDK + ks + kb);
#pragma unroll
            for (int nt = 0; nt < NT; ++nt) {
                bf16x8 bfv = *(const bf16x8*)(Bs + (nt * 16 + (lane & 15)) * LDK + ks + kb);
                acc[nt] = __builtin_amdgcn_mfma_f32_16x16x32_bf16(af, bfv, acc[nt], 0, 0, 0);
            }
        }
        __syncthreads();
    }
    // C/D: col = lane&15, row = (lane>>4)*4 + reg
    const int crow0 = row0 + wave * 16 + ((lane >> 4) << 2);
#pragma unroll
    for (int nt = 0; nt < NT; ++nt) {
        const int col = col0 + nt * 16 + (lane & 15);
#pragma unroll
        for (int j = 0; j < 4; ++j) {
            const int row = crow0 + j;
            if (row < M) {
                size_t off = INTERLEAVE
                    ? (size_t)row * 256 + (size_t)(col & 63) * 4 + (col >> 6)
                    : (size_t)row * Nfull + col;
                C[off] = f2us(acc[nt][j]);
            }
        }
    }
    // fused alpha: per-row per-head dots (requires BN == Nfull, col0 == 0)
    if constexpr (NHEAD > 0) {
        constexpr int NTL = NT / NHEAD;         // nt per head
        float sc[NT], dc[NT];
#pragma unroll
        for (int nt = 0; nt < NT; ++nt) {
            sc[nt] = att_src[nt * 16 + (lane & 15)];
            dc[nt] = att_dst[nt * 16 + (lane & 15)];
        }
#pragma unroll
        for (int j = 0; j < 4; ++j) {
            const int row = crow0 + j;
            float hs[NHEAD], hd[NHEAD];
#pragma unroll
            for (int h = 0; h < NHEAD; ++h) {
                float vs = 0.f, vd = 0.f;
#pragma unroll
                for (int t = 0; t < NTL; ++t) {
                    int nt = h * NTL + t;
                    vs += acc[nt][j] * sc[nt];
                    vd += acc[nt][j] * dc[nt];
                }
#pragma unroll
                for (int off = 1; off < 16; off <<= 1) {
                    vs += __shfl_xor(vs, off, 64);
                    vd += __shfl_xor(vd, off, 64);
                }
                hs[h] = vs; hd[h] = vd;
            }
            if ((lane & 15) == 0 && row < M) {
                if constexpr (NHEAD == 4) {
                    *(float4*)(as_out + (size_t)row * 4) = make_float4(hs[0], hs[1], hs[2], hs[3]);
                    *(float4*)(ad_out + (size_t)row * 4) = make_float4(hd[0], hd[1], hd[2], hd[3]);
                } else {
                    as_out[row] = hs[0];
                    ad_out[row] = hd[0];
                }
            }
        }
    }
}

// ---------------- CSR build ----------------
__global__ void deg_count_kernel(const int* __restrict__ dst, int* __restrict__ deg, int E) {
    int e = blockIdx.x * 256 + threadIdx.x;
    if (e < E) atomicAdd(&deg[dst[e]], 1);
}
__global__ __launch_bounds__(256) void scan1_kernel(const int* __restrict__ deg,
                                                    int* __restrict__ bsum, int N) {
    const int i = blockIdx.x * 256 + threadIdx.x;
    const int lane = threadIdx.x & 63, w = threadIdx.x >> 6;
    int v = (i < N) ? deg[i] : 0;
#pragma unroll
    for (int off = 32; off; off >>= 1) v += __shfl_xor(v, off, 64);
    __shared__ int ws[4];
    if (lane == 0) ws[w] = v;
    __syncthreads();
    if (threadIdx.x == 0) bsum[blockIdx.x] = ws[0] + ws[1] + ws[2] + ws[3];
}
__global__ __launch_bounds__(256) void scan2_kernel(const int* __restrict__ bsum,
                                                    int* __restrict__ boff, int nb) {
    const int tid = threadIdx.x, lane = tid & 63, w = tid >> 6;
    int v = (tid < nb) ? bsum[tid] : 0;
    int x = v;
#pragma unroll
    for (int off = 1; off < 64; off <<= 1) {
        int y = __shfl_up(x, off, 64);
        if (lane >= off) x += y;
    }
    __shared__ int ws[4];
    if (lane == 63) ws[w] = x;
    __syncthreads();
    int add = 0;
    for (int i = 0; i < w; ++i) add += ws[i];
    x += add;
    if (tid < nb) boff[tid] = x - v;      // exclusive
    if (tid == 255) boff[nb] = x;         // total
}
// scan3 + selfloop fused: writes row_ptr, self-loop edge, and fill.
__global__ __launch_bounds__(256) void scan3_kernel(const int* __restrict__ deg,
                                                    const int* __restrict__ boff,
                                                    int* __restrict__ row_ptr,
                                                    int2* __restrict__ edgeA,
                                                    int* __restrict__ fill, int N) {
    const int i = blockIdx.x * 256 + threadIdx.x;
    const int tid = threadIdx.x, lane = tid & 63, w = tid >> 6;
    int v = (i < N) ? deg[i] : 0;
    int x = v;
#pragma unroll
    for (int off = 1; off < 64; off <<= 1) {
        int y = __shfl_up(x, off, 64);
        if (lane >= off) x += y;
    }
    __shared__ int ws[4];
    if (lane == 63) ws[w] = x;
    __syncthreads();
    int add = 0;
    for (int k = 0; k < w; ++k) add += ws[k];
    x += add;
    int excl = x - v + boff[blockIdx.x];
    if (i < N) {
        row_ptr[i] = excl;
        edgeA[excl] = make_int2(i, i);    // self loop first
        fill[i] = excl + 1;
    }
    if (i == N - 1) row_ptr[N] = excl + v;
}
__global__ void scatter_kernel(const int* __restrict__ src, const int* __restrict__ dst,
                               int* __restrict__ fill, int2* __restrict__ edgeA, int E) {
    int e = blockIdx.x * 256 + threadIdx.x;
    if (e < E) {
        int d = dst[e];
        int pos = atomicAdd(&fill[d], 1);
        edgeA[pos] = make_int2(src[e], d);   // one 8B write
    }
}

// ---------------- edge-parallel softmax-weight precompute ----------------
template <int H>
__global__ __launch_bounds__(256) void wkernel(const int2* __restrict__ edgeA,
                                               const float* __restrict__ as,
                                               const float* __restrict__ ad,
                                               float* __restrict__ wA, int NNZ) {
    int p = blockIdx.x * 256 + threadIdx.x;
    if (p >= NNZ) return;
    const int2 e2 = edgeA[p];
    const int src = e2.x, dst = e2.y;
    if constexpr (H == 4) {
        float4 s = *(const float4*)(as + (size_t)src * 4);
        float4 d = *(const float4*)(ad + (size_t)dst * 4);
        float e;
        float4 w;
        e = s.x + d.x; e = e > 0.f ? e : 0.2f * e; w.x = __expf(e);
        e = s.y + d.y; e = e > 0.f ? e : 0.2f * e; w.y = __expf(e);
        e = s.z + d.z; e = e > 0.f ? e : 0.2f * e; w.z = __expf(e);
        e = s.w + d.w; e = e > 0.f ? e : 0.2f * e; w.w = __expf(e);
        *(float4*)(wA + (size_t)p * 4) = w;
    } else {
        float e = as[src] + ad[dst];
        e = e > 0.f ? e : 0.2f * e;
        wA[p] = __expf(e);
    }
}

// ---------------- layer-1 aggregation: 1 wave/node, 12-deep -----------------
#define B1 12
__global__ __launch_bounds__(256) void agg1_kernel(
    const unsigned short* __restrict__ g1, const float* __restrict__ wA,
    const int* __restrict__ row_ptr, const int2* __restrict__ edgeA,
    const float* __restrict__ b1, unsigned short* __restrict__ h1b, int N) {
    int wid = (blockIdx.x * 256 + threadIdx.x) >> 6;
    int lane = threadIdx.x & 63;
    if (wid >= N) return;
    float s0 = 0.f, s1 = 0.f, s2 = 0.f, s3 = 0.f;
    float a0 = 0.f, a1 = 0.f, a2 = 0.f, a3 = 0.f;
    const int beg = row_ptr[wid], end = row_ptr[wid + 1];
    for (int idx = beg; idx < end; idx += B1) {
        int p[B1];
#pragma unroll
        for (int j = 0; j < B1; ++j) { int q = idx + j; p[j] = q < end ? q : end - 1; }
        int si[B1];
#pragma unroll
        for (int j = 0; j < B1; ++j) si[j] = edgeA[p[j]].x;
        float4 w[B1];
#pragma unroll
        for (int j = 0; j < B1; ++j) w[j] = *(const float4*)(wA + (size_t)p[j] * 4);
        ushort4 g[B1];
#pragma unroll
        for (int j = 0; j < B1; ++j)
            g[j] = *(const ushort4*)(g1 + ((size_t)si[j] << 8) + lane * 4);
#pragma unroll
        for (int j = 0; j < B1; ++j) {
            const float m = (idx + j < end) ? 1.f : 0.f;
            const float wx = w[j].x * m, wy = w[j].y * m;
            const float wz = w[j].z * m, ww = w[j].w * m;
            s0 += wx; a0 += wx * us2f(g[j].x);
            s1 += wy; a1 += wy * us2f(g[j].y);
            s2 += wz; a2 += wz * us2f(g[j].z);
            s3 += ww; a3 += ww * us2f(g[j].w);
        }
    }
    size_t base = (size_t)wid * 256;
    float o;
    o = a0 / s0 + b1[lane];       o = o > 0.f ? o : expm1f(o); h1b[base + lane]       = f2us(o);
    o = a1 / s1 + b1[64 + lane];  o = o > 0.f ? o : expm1f(o); h1b[base + 64 + lane]  = f2us(o);
    o = a2 / s2 + b1[128 + lane]; o = o > 0.f ? o : expm1f(o); h1b[base + 128 + lane] = f2us(o);
    o = a3 / s3 + b1[192 + lane]; o = o > 0.f ? o : expm1f(o); h1b[base + 192 + lane] = f2us(o);
}

// ---------------- layer-2 aggregation + classifier: 1 wave/node, 32-deep ---
#define B2 32
__global__ __launch_bounds__(256) void agg2_kernel(
    const unsigned short* __restrict__ g2, const float* __restrict__ wA,
    const int* __restrict__ row_ptr, const int2* __restrict__ edgeA,
    const float* __restrict__ b2, const float* __restrict__ Wc,
    const float* __restrict__ bc, float* __restrict__ out, int N) {
    int wid = (blockIdx.x * 256 + threadIdx.x) >> 6;
    int lane = threadIdx.x & 63;
    if (wid >= N) return;
    float s = 0.f, a = 0.f;
    const int beg = row_ptr[wid], end = row_ptr[wid + 1];
    for (int idx = beg; idx < end; idx += B2) {
        int p[B2];
#pragma unroll
        for (int j = 0; j < B2; ++j) { int q = idx + j; p[j] = q < end ? q : end - 1; }
        int si[B2];
#pragma unroll
        for (int j = 0; j < B2; ++j) si[j] = edgeA[p[j]].x;
        float w[B2];
#pragma unroll
        for (int j = 0; j < B2; ++j) w[j] = wA[p[j]];
        unsigned short g[B2];
#pragma unroll
        for (int j = 0; j < B2; ++j) g[j] = g2[((size_t)si[j] << 6) + lane];
#pragma unroll
        for (int j = 0; j < B2; ++j) {
            const float m = (idx + j < end) ? 1.f : 0.f;
            const float wj = w[j] * m;
            s += wj; a += wj * us2f(g[j]);
        }
    }
    float h = a / s + b2[lane];
    h = h > 0.f ? h : expm1f(h);
    float c0 = h * Wc[lane * 2 + 0];
    float c1 = h * Wc[lane * 2 + 1];
#pragma unroll
    for (int off = 32; off; off >>= 1) {
        c0 += __shfl_xor(c0, off, 64);
        c1 += __shfl_xor(c1, off, 64);
    }
    if (lane == 0) {
        out[(size_t)wid * 2 + 0] = c0 + bc[0];
        out[(size_t)wid * 2 + 1] = c1 + bc[1];
    }
}

extern "C" void kernel_launch(void* const* d_in, const int* in_sizes, int n_in,
                              void* d_out, int out_size, void* d_ws, size_t ws_size,
                              hipStream_t stream) {
    const float* x        = (const float*)d_in[0];
    const int*   ei       = (const int*)d_in[1];
    const float* W1       = (const float*)d_in[2];
    const float* att1_src = (const float*)d_in[3];
    const float* att1_dst = (const float*)d_in[4];
    const float* b1       = (const float*)d_in[5];
    const float* W2       = (const float*)d_in[6];
    const float* att2_src = (const float*)d_in[7];
    const float* att2_dst = (const float*)d_in[8];
    const float* b2       = (const float*)d_in[9];
    const float* Wc       = (const float*)d_in[10];
    const float* bc       = (const float*)d_in[11];
    float* out = (float*)d_out;

    const int N = in_sizes[0] / IN_DIM;
    const int E = in_sizes[1] / 2;
    const int NNZ = E + N;
    const int* srcI = ei;
    const int* dstI = ei + E;

    // workspace layout (~85 MB): bf16 bufs | fp32 | edgeA(int2) | ints
    unsigned short* g1b = (unsigned short*)d_ws;      // N*256 (head-interleaved)
    unsigned short* h1b = g1b + (size_t)N * 256;      // N*256
    unsigned short* g2b = h1b + (size_t)N * 256;      // N*64
    unsigned short* W1T = g2b + (size_t)N * 64;       // 256*128
    unsigned short* W2T = W1T + 256 * 128;            // 64*256
    float* as1 = (float*)(W2T + 64 * 256);            // N*4
    float* ad1 = as1 + (size_t)N * 4;                 // N*4
    float* as2 = ad1 + (size_t)N * 4;                 // N
    float* ad2 = as2 + N;                             // N
    float* wA1 = ad2 + N;                             // NNZ*4 (16B-aligned)
    float* wA2 = wA1 + (size_t)NNZ * 4;               // NNZ
    int2* edgeA  = (int2*)(wA2 + NNZ);                // NNZ (8B-aligned)
    int* deg     = (int*)(edgeA + NNZ);               // N
    int* row_ptr = deg + N;                           // N+1
    int* fill    = row_ptr + N + 1;                   // N
    int* bsum    = fill + N;                          // 256
    int* boff    = bsum + 256;                        // 257

    const int nB = (N + 255) / 256;
    const int eB = (E + 255) / 256;
    const int pB = (NNZ + 255) / 256;
    const int wB = ((N * 64) + 255) / 256;            // one wave per node
    const int nb = nB;                                // scan partials (<=256)

    // setup (deg init + weight transposes)
    setup_kernel<<<nB, 256, 0, stream>>>(W1, W2, W1T, W2T, deg, N);

    // CSR build (selfloop fused into scan3)
    deg_count_kernel<<<eB, 256, 0, stream>>>(dstI, deg, E);
    scan1_kernel<<<nB, 256, 0, stream>>>(deg, bsum, N);
    scan2_kernel<<<1, 256, 0, stream>>>(bsum, boff, nb);
    scan3_kernel<<<nB, 256, 0, stream>>>(deg, boff, row_ptr, edgeA, fill, N);
    scatter_kernel<<<eB, 256, 0, stream>>>(srcI, dstI, fill, edgeA, E);

    // layer 1: g1 = x @ W1 (fp32 A staged to bf16), head-interleaved out,
    // alpha1 fused into epilogue (BN=256 = full width)
    gemm_mfma_kernel<256, 64, 128, true, true, 4>
        <<<dim3(1, (N + 63) / 64), 256, 0, stream>>>(x, W1T, g1b,
                                                     att1_src, att1_dst, as1, ad1, N, 256);
    wkernel<4><<<pB, 256, 0, stream>>>(edgeA, as1, ad1, wA1, NNZ);
    agg1_kernel<<<wB, 256, 0, stream>>>(g1b, wA1, row_ptr, edgeA, b1, h1b, N);

    // layer 2: g2 = h1 @ W2, alpha2 fused into epilogue (BN=64 = full width)
    gemm_mfma_kernel<64, 128, 256, false, false, 1>
        <<<dim3(1, (N + 63) / 64), 256, 0, stream>>>(h1b, W2T, g2b,
                                                     att2_src, att2_dst, as2, ad2, N, 64);
    wkernel<1><<<pB, 256, 0, stream>>>(edgeA, as2, ad2, wA2, NNZ);
    agg2_kernel<<<wB, 256, 0, stream>>>(g2b, wA2, row_ptr, edgeA, b2, Wc, bc, out, N);
}

// Round 11
// 374.634 us; speedup vs baseline: 1.0702x; 1.0702x over previous
//
#include <hip/hip_runtime.h>
#include <hip/hip_bf16.h>
#include <cstddef>

// ToxicityGAT: 2-layer GAT (4 heads -> 1 head) + linear classifier.
// N=50000, E=800000 (+N self loops), IN=128, HID=64, HEADS=4.
// R11: agg batches reverted to 8/16 (R10: depth 12/32 regressed - occupancy
// /issue loss). NEW: agg1 split into two head-pair passes over two 12.8 MB
// tables (g1b0: heads 0,1; g1b1: heads 2,3) - same total gather bytes,
// half working set per pass => higher L2 hit rate on the 195 MB miss path.

#define HEADS 4
#define HID 64
#define IN_DIM 128

using bf16x8 = __attribute__((ext_vector_type(8))) short;
using f32x4  = __attribute__((ext_vector_type(4))) float;

__device__ __forceinline__ float us2f(unsigned short u) {
    return __uint_as_float((unsigned int)u << 16);
}
__device__ __forceinline__ unsigned short f2us(float f) {
    __hip_bfloat16 b = __float2bfloat16(f);
    return __builtin_bit_cast(unsigned short, b);
}

// ---------------- setup: deg init + W1/W2 transpose+bf16 (one launch) ------
__global__ __launch_bounds__(256) void setup_kernel(const float* __restrict__ W1,
                                                    const float* __restrict__ W2,
                                                    unsigned short* __restrict__ W1T,
                                                    unsigned short* __restrict__ W2T,
                                                    int* __restrict__ deg, int N) {
    int i = blockIdx.x * 256 + threadIdx.x;
    if (i < N) deg[i] = 1;                       // self loop
    if (i < IN_DIM * 256) {                      // W1 [128][256] -> W1T [256][128]
        int k = i >> 8, n = i & 255;
        W1T[n * IN_DIM + k] = f2us(W1[i]);
    }
    if (i < 256 * 64) {                          // W2 [256][64] -> W2T [64][256]
        int k = i >> 6, n = i & 63;
        W2T[n * 256 + k] = f2us(W2[i]);
    }
}

// ---------------- MFMA GEMM + fused alpha dots ------------------------------
// C = A @ BT^T. AF32: A fp32->bf16 during staging.
// INTERLEAVE: split head-pair tables C (heads 0,1) / C2 (heads 2,3), each
// [n][d][2] bf16. NHEAD>0: epilogue per-row per-head dots (BN == Nfull).
template <int BN, int BK, int KFULL, bool INTERLEAVE, bool AF32, int NHEAD>
__global__ __launch_bounds__(256) void gemm_mfma_kernel(
    const void* __restrict__ Av,
    const unsigned short* __restrict__ BT,
    unsigned short* __restrict__ C,
    unsigned short* __restrict__ C2,
    const float* __restrict__ att_src, const float* __restrict__ att_dst,
    float* __restrict__ as_out, float* __restrict__ ad_out,
    int M, int Nfull) {
    constexpr int LDK = BK + 8;
    constexpr int NT = BN / 16;
    constexpr int KC = BK / 8;
    __shared__ unsigned short As[64 * LDK];
    __shared__ unsigned short Bs[BN * LDK];
    const int tid = threadIdx.x;
    const int wave = tid >> 6, lane = tid & 63;
    const int row0 = blockIdx.y * 64;
    const int col0 = blockIdx.x * BN;
    f32x4 acc[NT] = {};
    for (int k0 = 0; k0 < KFULL; k0 += BK) {
        for (int c = tid; c < 64 * KC; c += 256) {
            int r = c / KC, kc = c - r * KC;
            int row = row0 + r; if (row >= M) row = M - 1;  // clamp: stay in-bounds
            if constexpr (AF32) {
                const float* src = (const float*)Av + (size_t)row * KFULL + k0 + kc * 8;
                float4 v0 = *(const float4*)(src);
                float4 v1 = *(const float4*)(src + 4);
                *(ushort4*)(As + r * LDK + kc * 8) =
                    make_ushort4(f2us(v0.x), f2us(v0.y), f2us(v0.z), f2us(v0.w));
                *(ushort4*)(As + r * LDK + kc * 8 + 4) =
                    make_ushort4(f2us(v1.x), f2us(v1.y), f2us(v1.z), f2us(v1.w));
            } else {
                *(bf16x8*)(As + r * LDK + kc * 8) =
                    *(const bf16x8*)((const unsigned short*)Av + (size_t)row * KFULL + k0 + kc * 8);
            }
        }
        for (int c = tid; c < BN * KC; c += 256) {
            int r = c / KC, kc = c - r * KC;
            *(bf16x8*)(Bs + r * LDK + kc * 8) =
                *(const bf16x8*)(BT + (size_t)(col0 + r) * KFULL + k0 + kc * 8);
        }
        __syncthreads();
        const int arow = wave * 16 + (lane & 15);
        const int kb = (lane >> 4) * 8;
#pragma unroll
        for (int ks = 0; ks < BK; ks += 32) {
            bf16x8 af = *(const bf16x8*)(As + arow * LDK + ks + kb);
#pragma unroll
            for (int nt = 0; nt < NT; ++nt) {
                bf16x8 bfv = *(const bf16x8*)(Bs + (nt * 16 + (lane & 15)) * LDK + ks + kb);
                acc[nt] = __builtin_amdgcn_mfma_f32_16x16x32_bf16(af, bfv, acc[nt], 0, 0, 0);
            }
        }
        __syncthreads();
    }
    // C/D: col = lane&15, row = (lane>>4)*4 + reg
    const int crow0 = row0 + wave * 16 + ((lane >> 4) << 2);
#pragma unroll
    for (int nt = 0; nt < NT; ++nt) {
        const int col = col0 + nt * 16 + (lane & 15);
#pragma unroll
        for (int j = 0; j < 4; ++j) {
            const int row = crow0 + j;
            if (row < M) {
                if constexpr (INTERLEAVE) {
                    const int d = col & 63, h = col >> 6;
                    unsigned short* t = (h & 2) ? C2 : C;
                    t[(size_t)row * 128 + d * 2 + (h & 1)] = f2us(acc[nt][j]);
                } else {
                    C[(size_t)row * Nfull + col] = f2us(acc[nt][j]);
                }
            }
        }
    }
    // fused alpha: per-row per-head dots (requires BN == Nfull, col0 == 0)
    if constexpr (NHEAD > 0) {
        constexpr int NTL = NT / NHEAD;         // nt per head
        float sc[NT], dc[NT];
#pragma unroll
        for (int nt = 0; nt < NT; ++nt) {
            sc[nt] = att_src[nt * 16 + (lane & 15)];
            dc[nt] = att_dst[nt * 16 + (lane & 15)];
        }
#pragma unroll
        for (int j = 0; j < 4; ++j) {
            const int row = crow0 + j;
            float hs[NHEAD], hd[NHEAD];
#pragma unroll
            for (int h = 0; h < NHEAD; ++h) {
                float vs = 0.f, vd = 0.f;
#pragma unroll
                for (int t = 0; t < NTL; ++t) {
                    int nt = h * NTL + t;
                    vs += acc[nt][j] * sc[nt];
                    vd += acc[nt][j] * dc[nt];
                }
#pragma unroll
                for (int off = 1; off < 16; off <<= 1) {
                    vs += __shfl_xor(vs, off, 64);
                    vd += __shfl_xor(vd, off, 64);
                }
                hs[h] = vs; hd[h] = vd;
            }
            if ((lane & 15) == 0 && row < M) {
                if constexpr (NHEAD == 4) {
                    *(float4*)(as_out + (size_t)row * 4) = make_float4(hs[0], hs[1], hs[2], hs[3]);
                    *(float4*)(ad_out + (size_t)row * 4) = make_float4(hd[0], hd[1], hd[2], hd[3]);
                } else {
                    as_out[row] = hs[0];
                    ad_out[row] = hd[0];
                }
            }
        }
    }
}

// ---------------- CSR build ----------------
__global__ void deg_count_kernel(const int* __restrict__ dst, int* __restrict__ deg, int E) {
    int e = blockIdx.x * 256 + threadIdx.x;
    if (e < E) atomicAdd(&deg[dst[e]], 1);
}
__global__ __launch_bounds__(256) void scan1_kernel(const int* __restrict__ deg,
                                                    int* __restrict__ bsum, int N) {
    const int i = blockIdx.x * 256 + threadIdx.x;
    const int lane = threadIdx.x & 63, w = threadIdx.x >> 6;
    int v = (i < N) ? deg[i] : 0;
#pragma unroll
    for (int off = 32; off; off >>= 1) v += __shfl_xor(v, off, 64);
    __shared__ int ws[4];
    if (lane == 0) ws[w] = v;
    __syncthreads();
    if (threadIdx.x == 0) bsum[blockIdx.x] = ws[0] + ws[1] + ws[2] + ws[3];
}
__global__ __launch_bounds__(256) void scan2_kernel(const int* __restrict__ bsum,
                                                    int* __restrict__ boff, int nb) {
    const int tid = threadIdx.x, lane = tid & 63, w = tid >> 6;
    int v = (tid < nb) ? bsum[tid] : 0;
    int x = v;
#pragma unroll
    for (int off = 1; off < 64; off <<= 1) {
        int y = __shfl_up(x, off, 64);
        if (lane >= off) x += y;
    }
    __shared__ int ws[4];
    if (lane == 63) ws[w] = x;
    __syncthreads();
    int add = 0;
    for (int i = 0; i < w; ++i) add += ws[i];
    x += add;
    if (tid < nb) boff[tid] = x - v;      // exclusive
    if (tid == 255) boff[nb] = x;         // total
}
// scan3 + selfloop fused: writes row_ptr, self-loop edge, and fill.
__global__ __launch_bounds__(256) void scan3_kernel(const int* __restrict__ deg,
                                                    const int* __restrict__ boff,
                                                    int* __restrict__ row_ptr,
                                                    int2* __restrict__ edgeA,
                                                    int* __restrict__ fill, int N) {
    const int i = blockIdx.x * 256 + threadIdx.x;
    const int tid = threadIdx.x, lane = tid & 63, w = tid >> 6;
    int v = (i < N) ? deg[i] : 0;
    int x = v;
#pragma unroll
    for (int off = 1; off < 64; off <<= 1) {
        int y = __shfl_up(x, off, 64);
        if (lane >= off) x += y;
    }
    __shared__ int ws[4];
    if (lane == 63) ws[w] = x;
    __syncthreads();
    int add = 0;
    for (int k = 0; k < w; ++k) add += ws[k];
    x += add;
    int excl = x - v + boff[blockIdx.x];
    if (i < N) {
        row_ptr[i] = excl;
        edgeA[excl] = make_int2(i, i);    // self loop first
        fill[i] = excl + 1;
    }
    if (i == N - 1) row_ptr[N] = excl + v;
}
__global__ void scatter_kernel(const int* __restrict__ src, const int* __restrict__ dst,
                               int* __restrict__ fill, int2* __restrict__ edgeA, int E) {
    int e = blockIdx.x * 256 + threadIdx.x;
    if (e < E) {
        int d = dst[e];
        int pos = atomicAdd(&fill[d], 1);
        edgeA[pos] = make_int2(src[e], d);   // one 8B write
    }
}

// ---------------- edge-parallel softmax-weight precompute ----------------
// H==4 writes two float2 arrays (head pairs) for the split agg1 passes.
template <int H>
__global__ __launch_bounds__(256) void wkernel(const int2* __restrict__ edgeA,
                                               const float* __restrict__ as,
                                               const float* __restrict__ ad,
                                               float* __restrict__ wA,
                                               float* __restrict__ wB, int NNZ) {
    int p = blockIdx.x * 256 + threadIdx.x;
    if (p >= NNZ) return;
    const int2 e2 = edgeA[p];
    const int src = e2.x, dst = e2.y;
    if constexpr (H == 4) {
        float4 s = *(const float4*)(as + (size_t)src * 4);
        float4 d = *(const float4*)(ad + (size_t)dst * 4);
        float e;
        float w0, w1, w2, w3;
        e = s.x + d.x; e = e > 0.f ? e : 0.2f * e; w0 = __expf(e);
        e = s.y + d.y; e = e > 0.f ? e : 0.2f * e; w1 = __expf(e);
        e = s.z + d.z; e = e > 0.f ? e : 0.2f * e; w2 = __expf(e);
        e = s.w + d.w; e = e > 0.f ? e : 0.2f * e; w3 = __expf(e);
        *(float2*)(wA + (size_t)p * 2) = make_float2(w0, w1);
        *(float2*)(wB + (size_t)p * 2) = make_float2(w2, w3);
    } else {
        float e = as[src] + ad[dst];
        e = e > 0.f ? e : 0.2f * e;
        wA[p] = __expf(e);
    }
}

// ---------------- layer-1 aggregation pass: 2 heads, 1 wave/node, 8-deep ----
#define B1 8
__global__ __launch_bounds__(256) void agg1_pass_kernel(
    const unsigned short* __restrict__ tbl,   // [N][64][2] bf16 (12.8 MB)
    const float* __restrict__ wpair,          // [NNZ][2]
    const int* __restrict__ row_ptr, const int2* __restrict__ edgeA,
    const float* __restrict__ b1, unsigned short* __restrict__ h1b,
    int hoff, int N) {
    int wid = (blockIdx.x * 256 + threadIdx.x) >> 6;
    int lane = threadIdx.x & 63;
    if (wid >= N) return;
    float s0 = 0.f, s1 = 0.f, a0 = 0.f, a1 = 0.f;
    const int beg = row_ptr[wid], end = row_ptr[wid + 1];
    for (int idx = beg; idx < end; idx += B1) {
        int p[B1];
#pragma unroll
        for (int j = 0; j < B1; ++j) { int q = idx + j; p[j] = q < end ? q : end - 1; }
        int si[B1];
#pragma unroll
        for (int j = 0; j < B1; ++j) si[j] = edgeA[p[j]].x;
        float2 w[B1];
#pragma unroll
        for (int j = 0; j < B1; ++j) w[j] = *(const float2*)(wpair + (size_t)p[j] * 2);
        ushort2 g[B1];
#pragma unroll
        for (int j = 0; j < B1; ++j)
            g[j] = *(const ushort2*)(tbl + ((size_t)si[j] << 7) + lane * 2);
#pragma unroll
        for (int j = 0; j < B1; ++j) {
            const float m = (idx + j < end) ? 1.f : 0.f;
            const float wx = w[j].x * m, wy = w[j].y * m;
            s0 += wx; a0 += wx * us2f(g[j].x);
            s1 += wy; a1 += wy * us2f(g[j].y);
        }
    }
    size_t base = (size_t)wid * 256 + hoff * 64;
    float o;
    o = a0 / s0 + b1[hoff * 64 + lane];
    o = o > 0.f ? o : expm1f(o); h1b[base + lane] = f2us(o);
    o = a1 / s1 + b1[hoff * 64 + 64 + lane];
    o = o > 0.f ? o : expm1f(o); h1b[base + 64 + lane] = f2us(o);
}

// ---------------- layer-2 aggregation + classifier: 1 wave/node, 16-deep ---
#define B2 16
__global__ __launch_bounds__(256) void agg2_kernel(
    const unsigned short* __restrict__ g2, const float* __restrict__ wA,
    const int* __restrict__ row_ptr, const int2* __restrict__ edgeA,
    const float* __restrict__ b2, const float* __restrict__ Wc,
    const float* __restrict__ bc, float* __restrict__ out, int N) {
    int wid = (blockIdx.x * 256 + threadIdx.x) >> 6;
    int lane = threadIdx.x & 63;
    if (wid >= N) return;
    float s = 0.f, a = 0.f;
    const int beg = row_ptr[wid], end = row_ptr[wid + 1];
    for (int idx = beg; idx < end; idx += B2) {
        int p[B2];
#pragma unroll
        for (int j = 0; j < B2; ++j) { int q = idx + j; p[j] = q < end ? q : end - 1; }
        int si[B2];
#pragma unroll
        for (int j = 0; j < B2; ++j) si[j] = edgeA[p[j]].x;
        float w[B2];
#pragma unroll
        for (int j = 0; j < B2; ++j) w[j] = wA[p[j]];
        unsigned short g[B2];
#pragma unroll
        for (int j = 0; j < B2; ++j) g[j] = g2[((size_t)si[j] << 6) + lane];
#pragma unroll
        for (int j = 0; j < B2; ++j) {
            const float m = (idx + j < end) ? 1.f : 0.f;
            const float wj = w[j] * m;
            s += wj; a += wj * us2f(g[j]);
        }
    }
    float h = a / s + b2[lane];
    h = h > 0.f ? h : expm1f(h);
    float c0 = h * Wc[lane * 2 + 0];
    float c1 = h * Wc[lane * 2 + 1];
#pragma unroll
    for (int off = 32; off; off >>= 1) {
        c0 += __shfl_xor(c0, off, 64);
        c1 += __shfl_xor(c1, off, 64);
    }
    if (lane == 0) {
        out[(size_t)wid * 2 + 0] = c0 + bc[0];
        out[(size_t)wid * 2 + 1] = c1 + bc[1];
    }
}

extern "C" void kernel_launch(void* const* d_in, const int* in_sizes, int n_in,
                              void* d_out, int out_size, void* d_ws, size_t ws_size,
                              hipStream_t stream) {
    const float* x        = (const float*)d_in[0];
    const int*   ei       = (const int*)d_in[1];
    const float* W1       = (const float*)d_in[2];
    const float* att1_src = (const float*)d_in[3];
    const float* att1_dst = (const float*)d_in[4];
    const float* b1       = (const float*)d_in[5];
    const float* W2       = (const float*)d_in[6];
    const float* att2_src = (const float*)d_in[7];
    const float* att2_dst = (const float*)d_in[8];
    const float* b2       = (const float*)d_in[9];
    const float* Wc       = (const float*)d_in[10];
    const float* bc       = (const float*)d_in[11];
    float* out = (float*)d_out;

    const int N = in_sizes[0] / IN_DIM;
    const int E = in_sizes[1] / 2;
    const int NNZ = E + N;
    const int* srcI = ei;
    const int* dstI = ei + E;

    // workspace layout (~85 MB): bf16 bufs | fp32 | edgeA(int2) | ints
    unsigned short* g1b0 = (unsigned short*)d_ws;     // N*128 (heads 0,1 interleaved)
    unsigned short* g1b1 = g1b0 + (size_t)N * 128;    // N*128 (heads 2,3 interleaved)
    unsigned short* h1b  = g1b1 + (size_t)N * 128;    // N*256
    unsigned short* g2b  = h1b + (size_t)N * 256;     // N*64
    unsigned short* W1T  = g2b + (size_t)N * 64;      // 256*128
    unsigned short* W2T  = W1T + 256 * 128;           // 64*256
    float* as1 = (float*)(W2T + 64 * 256);            // N*4
    float* ad1 = as1 + (size_t)N * 4;                 // N*4
    float* as2 = ad1 + (size_t)N * 4;                 // N
    float* ad2 = as2 + N;                             // N
    float* wA1a = ad2 + N;                            // NNZ*2 (8B-aligned)
    float* wA1b = wA1a + (size_t)NNZ * 2;             // NNZ*2
    float* wA2  = wA1b + (size_t)NNZ * 2;             // NNZ
    int2* edgeA  = (int2*)(wA2 + NNZ);                // NNZ (8B-aligned)
    int* deg     = (int*)(edgeA + NNZ);               // N
    int* row_ptr = deg + N;                           // N+1
    int* fill    = row_ptr + N + 1;                   // N
    int* bsum    = fill + N;                          // 256
    int* boff    = bsum + 256;                        // 257

    const int nB = (N + 255) / 256;
    const int eB = (E + 255) / 256;
    const int pB = (NNZ + 255) / 256;
    const int wB = ((N * 64) + 255) / 256;            // one wave per node
    const int nb = nB;                                // scan partials (<=256)

    // setup (deg init + weight transposes)
    setup_kernel<<<nB, 256, 0, stream>>>(W1, W2, W1T, W2T, deg, N);

    // CSR build (selfloop fused into scan3)
    deg_count_kernel<<<eB, 256, 0, stream>>>(dstI, deg, E);
    scan1_kernel<<<nB, 256, 0, stream>>>(deg, bsum, N);
    scan2_kernel<<<1, 256, 0, stream>>>(bsum, boff, nb);
    scan3_kernel<<<nB, 256, 0, stream>>>(deg, boff, row_ptr, edgeA, fill, N);
    scatter_kernel<<<eB, 256, 0, stream>>>(srcI, dstI, fill, edgeA, E);

    // layer 1: g1 = x @ W1 -> two head-pair tables, alpha1 fused in epilogue
    gemm_mfma_kernel<256, 64, 128, true, true, 4>
        <<<dim3(1, (N + 63) / 64), 256, 0, stream>>>(x, W1T, g1b0, g1b1,
                                                     att1_src, att1_dst, as1, ad1, N, 256);
    wkernel<4><<<pB, 256, 0, stream>>>(edgeA, as1, ad1, wA1a, wA1b, NNZ);
    agg1_pass_kernel<<<wB, 256, 0, stream>>>(g1b0, wA1a, row_ptr, edgeA, b1, h1b, 0, N);
    agg1_pass_kernel<<<wB, 256, 0, stream>>>(g1b1, wA1b, row_ptr, edgeA, b1, h1b, 2, N);

    // layer 2: g2 = h1 @ W2, alpha2 fused in epilogue
    gemm_mfma_kernel<64, 128, 256, false, false, 1>
        <<<dim3(1, (N + 63) / 64), 256, 0, stream>>>(h1b, W2T, g2b, nullptr,
                                                     att2_src, att2_dst, as2, ad2, N, 64);
    wkernel<1><<<pB, 256, 0, stream>>>(edgeA, as2, ad2, wA2, nullptr, NNZ);
    agg2_kernel<<<wB, 256, 0, stream>>>(g2b, wA2, row_ptr, edgeA, b2, Wc, bc, out, N);
}

// Round 13
// 369.119 us; speedup vs baseline: 1.0862x; 1.0149x over previous
//
#include <hip/hip_runtime.h>
#include <hip/hip_bf16.h>
#include <cstddef>

// ToxicityGAT: 2-layer GAT (4 heads -> 1 head) + linear classifier.
// N=50000, E=800000 (+N self loops), IN=128, HID=64, HEADS=4.
// R12 resubmit (infra timeout): R9 structure (best-known 363us) — 1 wave/node
// agg, B=8/16, single interleaved g1 table, fused alpha epilogues — plus
// scan3+selfloop fusion (R10) and inline agg2 weights (drops wkernel<1>).
// agg1 is at its structural floor: 195MB mixed traffic @ ~2.3TB/s; VALU
// (R3/R5), MLP depth (R6/R10), wave-split (R8), working-set split (R11)
// all measured; bf16 payload is the accuracy floor (R7: fp8 absmax fail).

#define HEADS 4
#define HID 64
#define IN_DIM 128

using bf16x8 = __attribute__((ext_vector_type(8))) short;
using f32x4  = __attribute__((ext_vector_type(4))) float;

__device__ __forceinline__ float us2f(unsigned short u) {
    return __uint_as_float((unsigned int)u << 16);
}
__device__ __forceinline__ unsigned short f2us(float f) {
    __hip_bfloat16 b = __float2bfloat16(f);
    return __builtin_bit_cast(unsigned short, b);
}

// ---------------- setup: deg init + W1/W2 transpose+bf16 (one launch) ------
__global__ __launch_bounds__(256) void setup_kernel(const float* __restrict__ W1,
                                                    const float* __restrict__ W2,
                                                    unsigned short* __restrict__ W1T,
                                                    unsigned short* __restrict__ W2T,
                                                    int* __restrict__ deg, int N) {
    int i = blockIdx.x * 256 + threadIdx.x;
    if (i < N) deg[i] = 1;                       // self loop
    if (i < IN_DIM * 256) {                      // W1 [128][256] -> W1T [256][128]
        int k = i >> 8, n = i & 255;
        W1T[n * IN_DIM + k] = f2us(W1[i]);
    }
    if (i < 256 * 64) {                          // W2 [256][64] -> W2T [64][256]
        int k = i >> 6, n = i & 63;
        W2T[n * 256 + k] = f2us(W2[i]);
    }
}

// ---------------- MFMA GEMM + fused alpha dots ------------------------------
// C = A @ BT^T. AF32: A fp32->bf16 during staging. INTERLEAVE: g1b[n][d][h].
// NHEAD>0: epilogue computes per-row per-head dots with att_src/att_dst
// (requires BN == Nfull so each wave owns full rows).
template <int BN, int BK, int KFULL, bool INTERLEAVE, bool AF32, int NHEAD>
__global__ __launch_bounds__(256) void gemm_mfma_kernel(
    const void* __restrict__ Av,
    const unsigned short* __restrict__ BT,
    unsigned short* __restrict__ C,
    const float* __restrict__ att_src, const float* __restrict__ att_dst,
    float* __restrict__ as_out, float* __restrict__ ad_out,
    int M, int Nfull) {
    constexpr int LDK = BK + 8;
    constexpr int NT = BN / 16;
    constexpr int KC = BK / 8;
    __shared__ unsigned short As[64 * LDK];
    __shared__ unsigned short Bs[BN * LDK];
    const int tid = threadIdx.x;
    const int wave = tid >> 6, lane = tid & 63;
    const int row0 = blockIdx.y * 64;
    const int col0 = blockIdx.x * BN;
    f32x4 acc[NT] = {};
    for (int k0 = 0; k0 < KFULL; k0 += BK) {
        for (int c = tid; c < 64 * KC; c += 256) {
            int r = c / KC, kc = c - r * KC;
            int row = row0 + r; if (row >= M) row = M - 1;  // clamp: stay in-bounds
            if constexpr (AF32) {
                const float* src = (const float*)Av + (size_t)row * KFULL + k0 + kc * 8;
                float4 v0 = *(const float4*)(src);
                float4 v1 = *(const float4*)(src + 4);
                *(ushort4*)(As + r * LDK + kc * 8) =
                    make_ushort4(f2us(v0.x), f2us(v0.y), f2us(v0.z), f2us(v0.w));
                *(ushort4*)(As + r * LDK + kc * 8 + 4) =
                    make_ushort4(f2us(v1.x), f2us(v1.y), f2us(v1.z), f2us(v1.w));
            } else {
                *(bf16x8*)(As + r * LDK + kc * 8) =
                    *(const bf16x8*)((const unsigned short*)Av + (size_t)row * KFULL + k0 + kc * 8);
            }
        }
        for (int c = tid; c < BN * KC; c += 256) {
            int r = c / KC, kc = c - r * KC;
            *(bf16x8*)(Bs + r * LDK + kc * 8) =
                *(const bf16x8*)(BT + (size_t)(col0 + r) * KFULL + k0 + kc * 8);
        }
        __syncthreads();
        const int arow = wave * 16 + (lane & 15);
        const int kb = (lane >> 4) * 8;
#pragma unroll
        for (int ks = 0; ks < BK; ks += 32) {
            bf16x8 af = *(const bf16x8*)(As + arow * LDK + ks + kb);
#pragma unroll
            for (int nt = 0; nt < NT; ++nt) {
                bf16x8 bfv = *(const bf16x8*)(Bs + (nt * 16 + (lane & 15)) * LDK + ks + kb);
                acc[nt] = __builtin_amdgcn_mfma_f32_16x16x32_bf16(af, bfv, acc[nt], 0, 0, 0);
            }
        }
        __syncthreads();
    }
    // C/D: col = lane&15, row = (lane>>4)*4 + reg
    const int crow0 = row0 + wave * 16 + ((lane >> 4) << 2);
#pragma unroll
    for (int nt = 0; nt < NT; ++nt) {
        const int col = col0 + nt * 16 + (lane & 15);
#pragma unroll
        for (int j = 0; j < 4; ++j) {
            const int row = crow0 + j;
            if (row < M) {
                size_t off = INTERLEAVE
                    ? (size_t)row * 256 + (size_t)(col & 63) * 4 + (col >> 6)
                    : (size_t)row * Nfull + col;
                C[off] = f2us(acc[nt][j]);
            }
        }
    }
    // fused alpha: per-row per-head dots (requires BN == Nfull, col0 == 0)
    if constexpr (NHEAD > 0) {
        constexpr int NTL = NT / NHEAD;         // nt per head
        float sc[NT], dc[NT];
#pragma unroll
        for (int nt = 0; nt < NT; ++nt) {
            sc[nt] = att_src[nt * 16 + (lane & 15)];
            dc[nt] = att_dst[nt * 16 + (lane & 15)];
        }
#pragma unroll
        for (int j = 0; j < 4; ++j) {
            const int row = crow0 + j;
            float hs[NHEAD], hd[NHEAD];
#pragma unroll
            for (int h = 0; h < NHEAD; ++h) {
                float vs = 0.f, vd = 0.f;
#pragma unroll
                for (int t = 0; t < NTL; ++t) {
                    int nt = h * NTL + t;
                    vs += acc[nt][j] * sc[nt];
                    vd += acc[nt][j] * dc[nt];
                }
#pragma unroll
                for (int off = 1; off < 16; off <<= 1) {
                    vs += __shfl_xor(vs, off, 64);
                    vd += __shfl_xor(vd, off, 64);
                }
                hs[h] = vs; hd[h] = vd;
            }
            if ((lane & 15) == 0 && row < M) {
                if constexpr (NHEAD == 4) {
                    *(float4*)(as_out + (size_t)row * 4) = make_float4(hs[0], hs[1], hs[2], hs[3]);
                    *(float4*)(ad_out + (size_t)row * 4) = make_float4(hd[0], hd[1], hd[2], hd[3]);
                } else {
                    as_out[row] = hs[0];
                    ad_out[row] = hd[0];
                }
            }
        }
    }
}

// ---------------- CSR build ----------------
__global__ void deg_count_kernel(const int* __restrict__ dst, int* __restrict__ deg, int E) {
    int e = blockIdx.x * 256 + threadIdx.x;
    if (e < E) atomicAdd(&deg[dst[e]], 1);
}
__global__ __launch_bounds__(256) void scan1_kernel(const int* __restrict__ deg,
                                                    int* __restrict__ bsum, int N) {
    const int i = blockIdx.x * 256 + threadIdx.x;
    const int lane = threadIdx.x & 63, w = threadIdx.x >> 6;
    int v = (i < N) ? deg[i] : 0;
#pragma unroll
    for (int off = 32; off; off >>= 1) v += __shfl_xor(v, off, 64);
    __shared__ int ws[4];
    if (lane == 0) ws[w] = v;
    __syncthreads();
    if (threadIdx.x == 0) bsum[blockIdx.x] = ws[0] + ws[1] + ws[2] + ws[3];
}
__global__ __launch_bounds__(256) void scan2_kernel(const int* __restrict__ bsum,
                                                    int* __restrict__ boff, int nb) {
    const int tid = threadIdx.x, lane = tid & 63, w = tid >> 6;
    int v = (tid < nb) ? bsum[tid] : 0;
    int x = v;
#pragma unroll
    for (int off = 1; off < 64; off <<= 1) {
        int y = __shfl_up(x, off, 64);
        if (lane >= off) x += y;
    }
    __shared__ int ws[4];
    if (lane == 63) ws[w] = x;
    __syncthreads();
    int add = 0;
    for (int i = 0; i < w; ++i) add += ws[i];
    x += add;
    if (tid < nb) boff[tid] = x - v;      // exclusive
    if (tid == 255) boff[nb] = x;         // total
}
// scan3 + selfloop fused: writes row_ptr, self-loop edge, and fill.
__global__ __launch_bounds__(256) void scan3_kernel(const int* __restrict__ deg,
                                                    const int* __restrict__ boff,
                                                    int* __restrict__ row_ptr,
                                                    int2* __restrict__ edgeA,
                                                    int* __restrict__ fill, int N) {
    const int i = blockIdx.x * 256 + threadIdx.x;
    const int tid = threadIdx.x, lane = tid & 63, w = tid >> 6;
    int v = (i < N) ? deg[i] : 0;
    int x = v;
#pragma unroll
    for (int off = 1; off < 64; off <<= 1) {
        int y = __shfl_up(x, off, 64);
        if (lane >= off) x += y;
    }
    __shared__ int ws[4];
    if (lane == 63) ws[w] = x;
    __syncthreads();
    int add = 0;
    for (int k = 0; k < w; ++k) add += ws[k];
    x += add;
    int excl = x - v + boff[blockIdx.x];
    if (i < N) {
        row_ptr[i] = excl;
        edgeA[excl] = make_int2(i, i);    // self loop first
        fill[i] = excl + 1;
    }
    if (i == N - 1) row_ptr[N] = excl + v;
}
__global__ void scatter_kernel(const int* __restrict__ src, const int* __restrict__ dst,
                               int* __restrict__ fill, int2* __restrict__ edgeA, int E) {
    int e = blockIdx.x * 256 + threadIdx.x;
    if (e < E) {
        int d = dst[e];
        int pos = atomicAdd(&fill[d], 1);
        edgeA[pos] = make_int2(src[e], d);   // one 8B write
    }
}

// ---------------- edge-parallel softmax-weight precompute (layer 1) --------
__global__ __launch_bounds__(256) void wkernel4(const int2* __restrict__ edgeA,
                                                const float* __restrict__ as,
                                                const float* __restrict__ ad,
                                                float* __restrict__ wA, int NNZ) {
    int p = blockIdx.x * 256 + threadIdx.x;
    if (p >= NNZ) return;
    const int2 e2 = edgeA[p];
    float4 s = *(const float4*)(as + (size_t)e2.x * 4);
    float4 d = *(const float4*)(ad + (size_t)e2.y * 4);
    float e;
    float4 w;
    e = s.x + d.x; e = e > 0.f ? e : 0.2f * e; w.x = __expf(e);
    e = s.y + d.y; e = e > 0.f ? e : 0.2f * e; w.y = __expf(e);
    e = s.z + d.z; e = e > 0.f ? e : 0.2f * e; w.z = __expf(e);
    e = s.w + d.w; e = e > 0.f ? e : 0.2f * e; w.w = __expf(e);
    *(float4*)(wA + (size_t)p * 4) = w;
}

// ---------------- layer-1 aggregation: 1 wave/node, 8-deep (best-known) ----
#define B1 8
__global__ __launch_bounds__(256) void agg1_kernel(
    const unsigned short* __restrict__ g1, const float* __restrict__ wA,
    const int* __restrict__ row_ptr, const int2* __restrict__ edgeA,
    const float* __restrict__ b1, unsigned short* __restrict__ h1b, int N) {
    int wid = (blockIdx.x * 256 + threadIdx.x) >> 6;
    int lane = threadIdx.x & 63;
    if (wid >= N) return;
    float s0 = 0.f, s1 = 0.f, s2 = 0.f, s3 = 0.f;
    float a0 = 0.f, a1 = 0.f, a2 = 0.f, a3 = 0.f;
    const int beg = row_ptr[wid], end = row_ptr[wid + 1];
    for (int idx = beg; idx < end; idx += B1) {
        int p[B1];
#pragma unroll
        for (int j = 0; j < B1; ++j) { int q = idx + j; p[j] = q < end ? q : end - 1; }
        int si[B1];
#pragma unroll
        for (int j = 0; j < B1; ++j) si[j] = edgeA[p[j]].x;
        float4 w[B1];
#pragma unroll
        for (int j = 0; j < B1; ++j) w[j] = *(const float4*)(wA + (size_t)p[j] * 4);
        ushort4 g[B1];
#pragma unroll
        for (int j = 0; j < B1; ++j)
            g[j] = *(const ushort4*)(g1 + ((size_t)si[j] << 8) + lane * 4);
#pragma unroll
        for (int j = 0; j < B1; ++j) {
            const float m = (idx + j < end) ? 1.f : 0.f;
            const float wx = w[j].x * m, wy = w[j].y * m;
            const float wz = w[j].z * m, ww = w[j].w * m;
            s0 += wx; a0 += wx * us2f(g[j].x);
            s1 += wy; a1 += wy * us2f(g[j].y);
            s2 += wz; a2 += wz * us2f(g[j].z);
            s3 += ww; a3 += ww * us2f(g[j].w);
        }
    }
    size_t base = (size_t)wid * 256;
    float o;
    o = a0 / s0 + b1[lane];       o = o > 0.f ? o : expm1f(o); h1b[base + lane]       = f2us(o);
    o = a1 / s1 + b1[64 + lane];  o = o > 0.f ? o : expm1f(o); h1b[base + 64 + lane]  = f2us(o);
    o = a2 / s2 + b1[128 + lane]; o = o > 0.f ? o : expm1f(o); h1b[base + 128 + lane] = f2us(o);
    o = a3 / s3 + b1[192 + lane]; o = o > 0.f ? o : expm1f(o); h1b[base + 192 + lane] = f2us(o);
}

// ---------------- layer-2 aggregation + classifier: inline weights ----------
// w computed in-loop from as2[src]+ad2[dst] (bit-identical fp32 inputs to the
// old wkernel<1>); kills one kernel + the wA2 stream. One wave-redundant exp
// per edge hides under the 16-deep gather batch (loop is latency-dominated).
#define B2 16
__global__ __launch_bounds__(256) void agg2_kernel(
    const unsigned short* __restrict__ g2, const float* __restrict__ as2,
    const float* __restrict__ ad2, const int* __restrict__ row_ptr,
    const int2* __restrict__ edgeA, const float* __restrict__ b2,
    const float* __restrict__ Wc, const float* __restrict__ bc,
    float* __restrict__ out, int N) {
    int wid = (blockIdx.x * 256 + threadIdx.x) >> 6;
    int lane = threadIdx.x & 63;
    if (wid >= N) return;
    const float ad = ad2[wid];
    float s = 0.f, a = 0.f;
    const int beg = row_ptr[wid], end = row_ptr[wid + 1];
    for (int idx = beg; idx < end; idx += B2) {
        int p[B2];
#pragma unroll
        for (int j = 0; j < B2; ++j) { int q = idx + j; p[j] = q < end ? q : end - 1; }
        int si[B2];
#pragma unroll
        for (int j = 0; j < B2; ++j) si[j] = edgeA[p[j]].x;
        float asv[B2];
#pragma unroll
        for (int j = 0; j < B2; ++j) asv[j] = as2[si[j]];
        unsigned short g[B2];
#pragma unroll
        for (int j = 0; j < B2; ++j) g[j] = g2[((size_t)si[j] << 6) + lane];
#pragma unroll
        for (int j = 0; j < B2; ++j) {
            float e = asv[j] + ad; e = e > 0.f ? e : 0.2f * e;
            const float m = (idx + j < end) ? 1.f : 0.f;
            const float wj = __expf(e) * m;
            s += wj; a += wj * us2f(g[j]);
        }
    }
    float h = a / s + b2[lane];
    h = h > 0.f ? h : expm1f(h);
    float c0 = h * Wc[lane * 2 + 0];
    float c1 = h * Wc[lane * 2 + 1];
#pragma unroll
    for (int off = 32; off; off >>= 1) {
        c0 += __shfl_xor(c0, off, 64);
        c1 += __shfl_xor(c1, off, 64);
    }
    if (lane == 0) {
        out[(size_t)wid * 2 + 0] = c0 + bc[0];
        out[(size_t)wid * 2 + 1] = c1 + bc[1];
    }
}

extern "C" void kernel_launch(void* const* d_in, const int* in_sizes, int n_in,
                              void* d_out, int out_size, void* d_ws, size_t ws_size,
                              hipStream_t stream) {
    const float* x        = (const float*)d_in[0];
    const int*   ei       = (const int*)d_in[1];
    const float* W1       = (const float*)d_in[2];
    const float* att1_src = (const float*)d_in[3];
    const float* att1_dst = (const float*)d_in[4];
    const float* b1       = (const float*)d_in[5];
    const float* W2       = (const float*)d_in[6];
    const float* att2_src = (const float*)d_in[7];
    const float* att2_dst = (const float*)d_in[8];
    const float* b2       = (const float*)d_in[9];
    const float* Wc       = (const float*)d_in[10];
    const float* bc       = (const float*)d_in[11];
    float* out = (float*)d_out;

    const int N = in_sizes[0] / IN_DIM;
    const int E = in_sizes[1] / 2;
    const int NNZ = E + N;
    const int* srcI = ei;
    const int* dstI = ei + E;

    // workspace layout (~82 MB): bf16 bufs | fp32 | edgeA(int2) | ints
    unsigned short* g1b = (unsigned short*)d_ws;      // N*256 (head-interleaved)
    unsigned short* h1b = g1b + (size_t)N * 256;      // N*256
    unsigned short* g2b = h1b + (size_t)N * 256;      // N*64
    unsigned short* W1T = g2b + (size_t)N * 64;       // 256*128
    unsigned short* W2T = W1T + 256 * 128;            // 64*256
    float* as1 = (float*)(W2T + 64 * 256);            // N*4
    float* ad1 = as1 + (size_t)N * 4;                 // N*4
    float* as2 = ad1 + (size_t)N * 4;                 // N
    float* ad2 = as2 + N;                             // N
    float* wA1 = ad2 + N;                             // NNZ*4 (16B-aligned)
    int2* edgeA  = (int2*)(wA1 + (size_t)NNZ * 4);    // NNZ (8B-aligned)
    int* deg     = (int*)(edgeA + NNZ);               // N
    int* row_ptr = deg + N;                           // N+1
    int* fill    = row_ptr + N + 1;                   // N
    int* bsum    = fill + N;                          // 256
    int* boff    = bsum + 256;                        // 257

    const int nB = (N + 255) / 256;
    const int eB = (E + 255) / 256;
    const int pB = (NNZ + 255) / 256;
    const int wB = ((N * 64) + 255) / 256;            // one wave per node
    const int nb = nB;                                // scan partials (<=256)

    // setup (deg init + weight transposes)
    setup_kernel<<<nB, 256, 0, stream>>>(W1, W2, W1T, W2T, deg, N);

    // CSR build (selfloop fused into scan3)
    deg_count_kernel<<<eB, 256, 0, stream>>>(dstI, deg, E);
    scan1_kernel<<<nB, 256, 0, stream>>>(deg, bsum, N);
    scan2_kernel<<<1, 256, 0, stream>>>(bsum, boff, nb);
    scan3_kernel<<<nB, 256, 0, stream>>>(deg, boff, row_ptr, edgeA, fill, N);
    scatter_kernel<<<eB, 256, 0, stream>>>(srcI, dstI, fill, edgeA, E);

    // layer 1: g1 = x @ W1 (fp32 A staged to bf16), head-interleaved out,
    // alpha1 fused into epilogue (BN=256 = full width)
    gemm_mfma_kernel<256, 64, 128, true, true, 4>
        <<<dim3(1, (N + 63) / 64), 256, 0, stream>>>(x, W1T, g1b,
                                                     att1_src, att1_dst, as1, ad1, N, 256);
    wkernel4<<<pB, 256, 0, stream>>>(edgeA, as1, ad1, wA1, NNZ);
    agg1_kernel<<<wB, 256, 0, stream>>>(g1b, wA1, row_ptr, edgeA, b1, h1b, N);

    // layer 2: g2 = h1 @ W2, alpha2 fused into epilogue, weights inline in agg2
    gemm_mfma_kernel<64, 128, 256, false, false, 1>
        <<<dim3(1, (N + 63) / 64), 256, 0, stream>>>(h1b, W2T, g2b,
                                                     att2_src, att2_dst, as2, ad2, N, 64);
    agg2_kernel<<<wB, 256, 0, stream>>>(g2b, as2, ad2, row_ptr, edgeA, b2, Wc, bc, out, N);
}

// Round 14
// 362.815 us; speedup vs baseline: 1.1051x; 1.0174x over previous
//
#include <hip/hip_runtime.h>
#include <hip/hip_bf16.h>
#include <cstddef>

// ToxicityGAT: 2-layer GAT (4 heads -> 1 head) + linear classifier.
// N=50000, E=800000 (+N self loops), IN=128, HID=64, HEADS=4.
// R14: wkernel4 fused into agg1 (inline per-edge leaky+exp from L2-resident
// as1/ad1 tables; same pattern as agg2's neutral fusion) — kills one launch
// + the 27 MB wA1 round trip. agg1 core structure unchanged (1 wave/node,
// 8-deep batch = 5-axis-verified floor at 195 MB / ~2.3 TB/s).

#define HEADS 4
#define HID 64
#define IN_DIM 128

using bf16x8 = __attribute__((ext_vector_type(8))) short;
using f32x4  = __attribute__((ext_vector_type(4))) float;

__device__ __forceinline__ float us2f(unsigned short u) {
    return __uint_as_float((unsigned int)u << 16);
}
__device__ __forceinline__ unsigned short f2us(float f) {
    __hip_bfloat16 b = __float2bfloat16(f);
    return __builtin_bit_cast(unsigned short, b);
}

// ---------------- setup: deg init + W1/W2 transpose+bf16 (one launch) ------
__global__ __launch_bounds__(256) void setup_kernel(const float* __restrict__ W1,
                                                    const float* __restrict__ W2,
                                                    unsigned short* __restrict__ W1T,
                                                    unsigned short* __restrict__ W2T,
                                                    int* __restrict__ deg, int N) {
    int i = blockIdx.x * 256 + threadIdx.x;
    if (i < N) deg[i] = 1;                       // self loop
    if (i < IN_DIM * 256) {                      // W1 [128][256] -> W1T [256][128]
        int k = i >> 8, n = i & 255;
        W1T[n * IN_DIM + k] = f2us(W1[i]);
    }
    if (i < 256 * 64) {                          // W2 [256][64] -> W2T [64][256]
        int k = i >> 6, n = i & 63;
        W2T[n * 256 + k] = f2us(W2[i]);
    }
}

// ---------------- MFMA GEMM + fused alpha dots ------------------------------
// C = A @ BT^T. AF32: A fp32->bf16 during staging. INTERLEAVE: g1b[n][d][h].
// NHEAD>0: epilogue computes per-row per-head dots with att_src/att_dst
// (requires BN == Nfull so each wave owns full rows).
template <int BN, int BK, int KFULL, bool INTERLEAVE, bool AF32, int NHEAD>
__global__ __launch_bounds__(256) void gemm_mfma_kernel(
    const void* __restrict__ Av,
    const unsigned short* __restrict__ BT,
    unsigned short* __restrict__ C,
    const float* __restrict__ att_src, const float* __restrict__ att_dst,
    float* __restrict__ as_out, float* __restrict__ ad_out,
    int M, int Nfull) {
    constexpr int LDK = BK + 8;
    constexpr int NT = BN / 16;
    constexpr int KC = BK / 8;
    __shared__ unsigned short As[64 * LDK];
    __shared__ unsigned short Bs[BN * LDK];
    const int tid = threadIdx.x;
    const int wave = tid >> 6, lane = tid & 63;
    const int row0 = blockIdx.y * 64;
    const int col0 = blockIdx.x * BN;
    f32x4 acc[NT] = {};
    for (int k0 = 0; k0 < KFULL; k0 += BK) {
        for (int c = tid; c < 64 * KC; c += 256) {
            int r = c / KC, kc = c - r * KC;
            int row = row0 + r; if (row >= M) row = M - 1;  // clamp: stay in-bounds
            if constexpr (AF32) {
                const float* src = (const float*)Av + (size_t)row * KFULL + k0 + kc * 8;
                float4 v0 = *(const float4*)(src);
                float4 v1 = *(const float4*)(src + 4);
                *(ushort4*)(As + r * LDK + kc * 8) =
                    make_ushort4(f2us(v0.x), f2us(v0.y), f2us(v0.z), f2us(v0.w));
                *(ushort4*)(As + r * LDK + kc * 8 + 4) =
                    make_ushort4(f2us(v1.x), f2us(v1.y), f2us(v1.z), f2us(v1.w));
            } else {
                *(bf16x8*)(As + r * LDK + kc * 8) =
                    *(const bf16x8*)((const unsigned short*)Av + (size_t)row * KFULL + k0 + kc * 8);
            }
        }
        for (int c = tid; c < BN * KC; c += 256) {
            int r = c / KC, kc = c - r * KC;
            *(bf16x8*)(Bs + r * LDK + kc * 8) =
                *(const bf16x8*)(BT + (size_t)(col0 + r) * KFULL + k0 + kc * 8);
        }
        __syncthreads();
        const int arow = wave * 16 + (lane & 15);
        const int kb = (lane >> 4) * 8;
#pragma unroll
        for (int ks = 0; ks < BK; ks += 32) {
            bf16x8 af = *(const bf16x8*)(As + arow * LDK + ks + kb);
#pragma unroll
            for (int nt = 0; nt < NT; ++nt) {
                bf16x8 bfv = *(const bf16x8*)(Bs + (nt * 16 + (lane & 15)) * LDK + ks + kb);
                acc[nt] = __builtin_amdgcn_mfma_f32_16x16x32_bf16(af, bfv, acc[nt], 0, 0, 0);
            }
        }
        __syncthreads();
    }
    // C/D: col = lane&15, row = (lane>>4)*4 + reg
    const int crow0 = row0 + wave * 16 + ((lane >> 4) << 2);
#pragma unroll
    for (int nt = 0; nt < NT; ++nt) {
        const int col = col0 + nt * 16 + (lane & 15);
#pragma unroll
        for (int j = 0; j < 4; ++j) {
            const int row = crow0 + j;
            if (row < M) {
                size_t off = INTERLEAVE
                    ? (size_t)row * 256 + (size_t)(col & 63) * 4 + (col >> 6)
                    : (size_t)row * Nfull + col;
                C[off] = f2us(acc[nt][j]);
            }
        }
    }
    // fused alpha: per-row per-head dots (requires BN == Nfull, col0 == 0)
    if constexpr (NHEAD > 0) {
        constexpr int NTL = NT / NHEAD;         // nt per head
        float sc[NT], dc[NT];
#pragma unroll
        for (int nt = 0; nt < NT; ++nt) {
            sc[nt] = att_src[nt * 16 + (lane & 15)];
            dc[nt] = att_dst[nt * 16 + (lane & 15)];
        }
#pragma unroll
        for (int j = 0; j < 4; ++j) {
            const int row = crow0 + j;
            float hs[NHEAD], hd[NHEAD];
#pragma unroll
            for (int h = 0; h < NHEAD; ++h) {
                float vs = 0.f, vd = 0.f;
#pragma unroll
                for (int t = 0; t < NTL; ++t) {
                    int nt = h * NTL + t;
                    vs += acc[nt][j] * sc[nt];
                    vd += acc[nt][j] * dc[nt];
                }
#pragma unroll
                for (int off = 1; off < 16; off <<= 1) {
                    vs += __shfl_xor(vs, off, 64);
                    vd += __shfl_xor(vd, off, 64);
                }
                hs[h] = vs; hd[h] = vd;
            }
            if ((lane & 15) == 0 && row < M) {
                if constexpr (NHEAD == 4) {
                    *(float4*)(as_out + (size_t)row * 4) = make_float4(hs[0], hs[1], hs[2], hs[3]);
                    *(float4*)(ad_out + (size_t)row * 4) = make_float4(hd[0], hd[1], hd[2], hd[3]);
                } else {
                    as_out[row] = hs[0];
                    ad_out[row] = hd[0];
                }
            }
        }
    }
}

// ---------------- CSR build ----------------
__global__ void deg_count_kernel(const int* __restrict__ dst, int* __restrict__ deg, int E) {
    int e = blockIdx.x * 256 + threadIdx.x;
    if (e < E) atomicAdd(&deg[dst[e]], 1);
}
__global__ __launch_bounds__(256) void scan1_kernel(const int* __restrict__ deg,
                                                    int* __restrict__ bsum, int N) {
    const int i = blockIdx.x * 256 + threadIdx.x;
    const int lane = threadIdx.x & 63, w = threadIdx.x >> 6;
    int v = (i < N) ? deg[i] : 0;
#pragma unroll
    for (int off = 32; off; off >>= 1) v += __shfl_xor(v, off, 64);
    __shared__ int ws[4];
    if (lane == 0) ws[w] = v;
    __syncthreads();
    if (threadIdx.x == 0) bsum[blockIdx.x] = ws[0] + ws[1] + ws[2] + ws[3];
}
__global__ __launch_bounds__(256) void scan2_kernel(const int* __restrict__ bsum,
                                                    int* __restrict__ boff, int nb) {
    const int tid = threadIdx.x, lane = tid & 63, w = tid >> 6;
    int v = (tid < nb) ? bsum[tid] : 0;
    int x = v;
#pragma unroll
    for (int off = 1; off < 64; off <<= 1) {
        int y = __shfl_up(x, off, 64);
        if (lane >= off) x += y;
    }
    __shared__ int ws[4];
    if (lane == 63) ws[w] = x;
    __syncthreads();
    int add = 0;
    for (int i = 0; i < w; ++i) add += ws[i];
    x += add;
    if (tid < nb) boff[tid] = x - v;      // exclusive
    if (tid == 255) boff[nb] = x;         // total
}
// scan3 + selfloop fused: writes row_ptr, self-loop edge, and fill.
__global__ __launch_bounds__(256) void scan3_kernel(const int* __restrict__ deg,
                                                    const int* __restrict__ boff,
                                                    int* __restrict__ row_ptr,
                                                    int2* __restrict__ edgeA,
                                                    int* __restrict__ fill, int N) {
    const int i = blockIdx.x * 256 + threadIdx.x;
    const int tid = threadIdx.x, lane = tid & 63, w = tid >> 6;
    int v = (i < N) ? deg[i] : 0;
    int x = v;
#pragma unroll
    for (int off = 1; off < 64; off <<= 1) {
        int y = __shfl_up(x, off, 64);
        if (lane >= off) x += y;
    }
    __shared__ int ws[4];
    if (lane == 63) ws[w] = x;
    __syncthreads();
    int add = 0;
    for (int k = 0; k < w; ++k) add += ws[k];
    x += add;
    int excl = x - v + boff[blockIdx.x];
    if (i < N) {
        row_ptr[i] = excl;
        edgeA[excl] = make_int2(i, i);    // self loop first
        fill[i] = excl + 1;
    }
    if (i == N - 1) row_ptr[N] = excl + v;
}
__global__ void scatter_kernel(const int* __restrict__ src, const int* __restrict__ dst,
                               int* __restrict__ fill, int2* __restrict__ edgeA, int E) {
    int e = blockIdx.x * 256 + threadIdx.x;
    if (e < E) {
        int d = dst[e];
        int pos = atomicAdd(&fill[d], 1);
        edgeA[pos] = make_int2(src[e], d);   // one 8B write
    }
}

// ---------------- layer-1 aggregation: 1 wave/node, 8-deep, inline weights --
// Weights computed in-loop: as1[src] gathered (800 KB L2-resident table),
// ad1[wid] loaded once per wave; leaky+exp wave-wide (hides under batch).
#define B1 8
__global__ __launch_bounds__(256) void agg1_kernel(
    const unsigned short* __restrict__ g1, const float* __restrict__ as1,
    const float* __restrict__ ad1, const int* __restrict__ row_ptr,
    const int2* __restrict__ edgeA, const float* __restrict__ b1,
    unsigned short* __restrict__ h1b, int N) {
    int wid = (blockIdx.x * 256 + threadIdx.x) >> 6;
    int lane = threadIdx.x & 63;
    if (wid >= N) return;
    const float4 adv = *(const float4*)(ad1 + (size_t)wid * 4);
    float s0 = 0.f, s1 = 0.f, s2 = 0.f, s3 = 0.f;
    float a0 = 0.f, a1 = 0.f, a2 = 0.f, a3 = 0.f;
    const int beg = row_ptr[wid], end = row_ptr[wid + 1];
    for (int idx = beg; idx < end; idx += B1) {
        int p[B1];
#pragma unroll
        for (int j = 0; j < B1; ++j) { int q = idx + j; p[j] = q < end ? q : end - 1; }
        int si[B1];
#pragma unroll
        for (int j = 0; j < B1; ++j) si[j] = edgeA[p[j]].x;
        float4 asv[B1];
#pragma unroll
        for (int j = 0; j < B1; ++j) asv[j] = *(const float4*)(as1 + (size_t)si[j] * 4);
        ushort4 g[B1];
#pragma unroll
        for (int j = 0; j < B1; ++j)
            g[j] = *(const ushort4*)(g1 + ((size_t)si[j] << 8) + lane * 4);
#pragma unroll
        for (int j = 0; j < B1; ++j) {
            const float m = (idx + j < end) ? 1.f : 0.f;
            float e;
            e = asv[j].x + adv.x; e = e > 0.f ? e : 0.2f * e;
            const float wx = __expf(e) * m;
            e = asv[j].y + adv.y; e = e > 0.f ? e : 0.2f * e;
            const float wy = __expf(e) * m;
            e = asv[j].z + adv.z; e = e > 0.f ? e : 0.2f * e;
            const float wz = __expf(e) * m;
            e = asv[j].w + adv.w; e = e > 0.f ? e : 0.2f * e;
            const float ww = __expf(e) * m;
            s0 += wx; a0 += wx * us2f(g[j].x);
            s1 += wy; a1 += wy * us2f(g[j].y);
            s2 += wz; a2 += wz * us2f(g[j].z);
            s3 += ww; a3 += ww * us2f(g[j].w);
        }
    }
    size_t base = (size_t)wid * 256;
    float o;
    o = a0 / s0 + b1[lane];       o = o > 0.f ? o : expm1f(o); h1b[base + lane]       = f2us(o);
    o = a1 / s1 + b1[64 + lane];  o = o > 0.f ? o : expm1f(o); h1b[base + 64 + lane]  = f2us(o);
    o = a2 / s2 + b1[128 + lane]; o = o > 0.f ? o : expm1f(o); h1b[base + 128 + lane] = f2us(o);
    o = a3 / s3 + b1[192 + lane]; o = o > 0.f ? o : expm1f(o); h1b[base + 192 + lane] = f2us(o);
}

// ---------------- layer-2 aggregation + classifier: inline weights ----------
#define B2 16
__global__ __launch_bounds__(256) void agg2_kernel(
    const unsigned short* __restrict__ g2, const float* __restrict__ as2,
    const float* __restrict__ ad2, const int* __restrict__ row_ptr,
    const int2* __restrict__ edgeA, const float* __restrict__ b2,
    const float* __restrict__ Wc, const float* __restrict__ bc,
    float* __restrict__ out, int N) {
    int wid = (blockIdx.x * 256 + threadIdx.x) >> 6;
    int lane = threadIdx.x & 63;
    if (wid >= N) return;
    const float ad = ad2[wid];
    float s = 0.f, a = 0.f;
    const int beg = row_ptr[wid], end = row_ptr[wid + 1];
    for (int idx = beg; idx < end; idx += B2) {
        int p[B2];
#pragma unroll
        for (int j = 0; j < B2; ++j) { int q = idx + j; p[j] = q < end ? q : end - 1; }
        int si[B2];
#pragma unroll
        for (int j = 0; j < B2; ++j) si[j] = edgeA[p[j]].x;
        float asv[B2];
#pragma unroll
        for (int j = 0; j < B2; ++j) asv[j] = as2[si[j]];
        unsigned short g[B2];
#pragma unroll
        for (int j = 0; j < B2; ++j) g[j] = g2[((size_t)si[j] << 6) + lane];
#pragma unroll
        for (int j = 0; j < B2; ++j) {
            float e = asv[j] + ad; e = e > 0.f ? e : 0.2f * e;
            const float m = (idx + j < end) ? 1.f : 0.f;
            const float wj = __expf(e) * m;
            s += wj; a += wj * us2f(g[j]);
        }
    }
    float h = a / s + b2[lane];
    h = h > 0.f ? h : expm1f(h);
    float c0 = h * Wc[lane * 2 + 0];
    float c1 = h * Wc[lane * 2 + 1];
#pragma unroll
    for (int off = 32; off; off >>= 1) {
        c0 += __shfl_xor(c0, off, 64);
        c1 += __shfl_xor(c1, off, 64);
    }
    if (lane == 0) {
        out[(size_t)wid * 2 + 0] = c0 + bc[0];
        out[(size_t)wid * 2 + 1] = c1 + bc[1];
    }
}

extern "C" void kernel_launch(void* const* d_in, const int* in_sizes, int n_in,
                              void* d_out, int out_size, void* d_ws, size_t ws_size,
                              hipStream_t stream) {
    const float* x        = (const float*)d_in[0];
    const int*   ei       = (const int*)d_in[1];
    const float* W1       = (const float*)d_in[2];
    const float* att1_src = (const float*)d_in[3];
    const float* att1_dst = (const float*)d_in[4];
    const float* b1       = (const float*)d_in[5];
    const float* W2       = (const float*)d_in[6];
    const float* att2_src = (const float*)d_in[7];
    const float* att2_dst = (const float*)d_in[8];
    const float* b2       = (const float*)d_in[9];
    const float* Wc       = (const float*)d_in[10];
    const float* bc       = (const float*)d_in[11];
    float* out = (float*)d_out;

    const int N = in_sizes[0] / IN_DIM;
    const int E = in_sizes[1] / 2;
    const int NNZ = E + N;
    const int* srcI = ei;
    const int* dstI = ei + E;

    // workspace layout (~68 MB): bf16 bufs | fp32 | edgeA(int2) | ints
    unsigned short* g1b = (unsigned short*)d_ws;      // N*256 (head-interleaved)
    unsigned short* h1b = g1b + (size_t)N * 256;      // N*256
    unsigned short* g2b = h1b + (size_t)N * 256;      // N*64
    unsigned short* W1T = g2b + (size_t)N * 64;       // 256*128
    unsigned short* W2T = W1T + 256 * 128;            // 64*256
    float* as1 = (float*)(W2T + 64 * 256);            // N*4
    float* ad1 = as1 + (size_t)N * 4;                 // N*4
    float* as2 = ad1 + (size_t)N * 4;                 // N
    float* ad2 = as2 + N;                             // N
    int2* edgeA  = (int2*)(ad2 + N);                  // NNZ (8B-aligned)
    int* deg     = (int*)(edgeA + NNZ);               // N
    int* row_ptr = deg + N;                           // N+1
    int* fill    = row_ptr + N + 1;                   // N
    int* bsum    = fill + N;                          // 256
    int* boff    = bsum + 256;                        // 257

    const int nB = (N + 255) / 256;
    const int eB = (E + 255) / 256;
    const int wB = ((N * 64) + 255) / 256;            // one wave per node
    const int nb = nB;                                // scan partials (<=256)

    // setup (deg init + weight transposes)
    setup_kernel<<<nB, 256, 0, stream>>>(W1, W2, W1T, W2T, deg, N);

    // CSR build (selfloop fused into scan3)
    deg_count_kernel<<<eB, 256, 0, stream>>>(dstI, deg, E);
    scan1_kernel<<<nB, 256, 0, stream>>>(deg, bsum, N);
    scan2_kernel<<<1, 256, 0, stream>>>(bsum, boff, nb);
    scan3_kernel<<<nB, 256, 0, stream>>>(deg, boff, row_ptr, edgeA, fill, N);
    scatter_kernel<<<eB, 256, 0, stream>>>(srcI, dstI, fill, edgeA, E);

    // layer 1: g1 = x @ W1 (fp32 A staged to bf16), head-interleaved out,
    // alpha1 fused into epilogue; weights inline in agg1 (wkernel4 gone)
    gemm_mfma_kernel<256, 64, 128, true, true, 4>
        <<<dim3(1, (N + 63) / 64), 256, 0, stream>>>(x, W1T, g1b,
                                                     att1_src, att1_dst, as1, ad1, N, 256);
    agg1_kernel<<<wB, 256, 0, stream>>>(g1b, as1, ad1, row_ptr, edgeA, b1, h1b, N);

    // layer 2: g2 = h1 @ W2, alpha2 fused into epilogue, weights inline in agg2
    gemm_mfma_kernel<64, 128, 256, false, false, 1>
        <<<dim3(1, (N + 63) / 64), 256, 0, stream>>>(h1b, W2T, g2b,
                                                     att2_src, att2_dst, as2, ad2, N, 64);
    agg2_kernel<<<wB, 256, 0, stream>>>(g2b, as2, ad2, row_ptr, edgeA, b2, Wc, bc, out, N);
}